// Round 2
// baseline (1173.022 us; speedup 1.0000x reference)
//
#include <hip/hip_runtime.h>

constexpr int kNAtoms = 50000;
constexpr int kNConf  = 500;
constexpr int kNRows  = 3000000;   // 3 * NPAIRS
constexpr int kND     = 55;
constexpr int kNDP    = 56;        // padded row stride for dEdD (224 B, 16B-aligned)
constexpr int kH      = 64;
constexpr int kOutN   = kNConf + 3 * kNAtoms;  // 150500

__global__ void zero_out_kernel(float* __restrict__ out, int n) {
  int i = blockIdx.x * blockDim.x + threadIdx.x;
  if (i < n) out[i] = 0.0f;
}

// One thread per atom: MLP forward + backward (VJP with ones cotangent).
// Weights staged in LDS; all weight reads are wave-uniform (broadcast) and
// 4-contiguous so the compiler can emit ds_read_b128.
// 128-thread blocks: 391 blocks spread over 256 CUs (vs 196 with 256-thread).
__global__ __launch_bounds__(128)
void mlp_kernel(const float* __restrict__ x,
                const int* __restrict__ indices,
                const float* __restrict__ W1, const float* __restrict__ b1,
                const float* __restrict__ W2, const float* __restrict__ b2,
                const float* __restrict__ W3, const float* __restrict__ b3,
                float* __restrict__ out_energy,   // [kNConf], pre-zeroed
                float* __restrict__ dEdD) {       // [kNAtoms * kNDP] workspace
  __shared__ float sW1[kND * kH];    // W1[d][k]
  __shared__ float sW2[kH * kH];     // W2[j][k]
  __shared__ float sW2T[kH * kH];    // W2T[k][j] = W2[j][k]
  __shared__ float sW3[kH];
  __shared__ float sb1[kH];
  __shared__ float sb2[kH];
  __shared__ float sb3s;

  const int t = threadIdx.x;
  for (int i = t; i < kND * kH; i += 128) sW1[i] = W1[i];
  for (int i = t; i < kH * kH; i += 128) sW2[i] = W2[i];
  // transposed copy: LDS-write conflict-free (linear dest), strided global read
  // (W2 is L2-hot; 16 KB/block is negligible traffic).
  for (int i = t; i < kH * kH; i += 128) {
    int k = i / kH, j = i % kH;             // dest sW2T[k*kH + j]
    sW2T[i] = W2[j * kH + k];
  }
  if (t < kH) { sW3[t] = W3[t]; sb1[t] = b1[t]; sb2[t] = b2[t]; }
  if (t == 0) sb3s = b3[0];
  __syncthreads();

  const int atom = blockIdx.x * 128 + t;
  if (atom >= kNAtoms) return;

  // ---- load descriptor row ----
  float xv[kND];
  #pragma unroll
  for (int d = 0; d < kND; ++d) xv[d] = x[atom * kND + d];

  // ---- layer 1: h1 = tanh(x @ W1 + b1) ----
  float h1[kH];
  #pragma unroll
  for (int k = 0; k < kH; k += 4) {
    float s0 = sb1[k+0], s1 = sb1[k+1], s2 = sb1[k+2], s3 = sb1[k+3];
    #pragma unroll
    for (int d = 0; d < kND; ++d) {
      const float xvd = xv[d];
      const float* w = &sW1[d * kH + k];   // 4 contiguous floats
      s0 += xvd * w[0]; s1 += xvd * w[1]; s2 += xvd * w[2]; s3 += xvd * w[3];
    }
    h1[k+0] = tanhf(s0); h1[k+1] = tanhf(s1);
    h1[k+2] = tanhf(s2); h1[k+3] = tanhf(s3);
  }

  // ---- layer 2: h2 = tanh(h1 @ W2 + b2); E = h2 @ W3 + b3 ----
  // da2[k] = W3[k] * (1 - h2[k]^2) computed in place (h2 never stored).
  float da2[kH];
  float energy = sb3s;
  #pragma unroll
  for (int k = 0; k < kH; k += 4) {
    float s0 = sb2[k+0], s1 = sb2[k+1], s2 = sb2[k+2], s3 = sb2[k+3];
    #pragma unroll
    for (int j = 0; j < kH; ++j) {
      const float hj = h1[j];
      const float* w = &sW2[j * kH + k];   // 4 contiguous floats
      s0 += hj * w[0]; s1 += hj * w[1]; s2 += hj * w[2]; s3 += hj * w[3];
    }
    const float t0 = tanhf(s0), t1 = tanhf(s1), t2 = tanhf(s2), t3 = tanhf(s3);
    energy += t0 * sW3[k+0] + t1 * sW3[k+1] + t2 * sW3[k+2] + t3 * sW3[k+3];
    da2[k+0] = sW3[k+0] * (1.0f - t0 * t0);
    da2[k+1] = sW3[k+1] * (1.0f - t1 * t1);
    da2[k+2] = sW3[k+2] * (1.0f - t2 * t2);
    da2[k+3] = sW3[k+3] * (1.0f - t3 * t3);
  }

  atomicAdd(&out_energy[indices[atom]], energy);

  // ---- backward layer 2: da1[j] = (1 - h1[j]^2) * sum_k da2[k] * W2[j][k] ----
  float da1[kH];
  #pragma unroll
  for (int j = 0; j < kH; j += 4) {
    float s0 = 0.f, s1 = 0.f, s2 = 0.f, s3 = 0.f;
    #pragma unroll
    for (int k = 0; k < kH; ++k) {
      const float g = da2[k];
      const float* w = &sW2T[k * kH + j];  // 4 contiguous floats
      s0 += g * w[0]; s1 += g * w[1]; s2 += g * w[2]; s3 += g * w[3];
    }
    const float t0 = h1[j+0], t1 = h1[j+1], t2 = h1[j+2], t3 = h1[j+3];
    da1[j+0] = s0 * (1.0f - t0 * t0);
    da1[j+1] = s1 * (1.0f - t1 * t1);
    da1[j+2] = s2 * (1.0f - t2 * t2);
    da1[j+3] = s3 * (1.0f - t3 * t3);
  }

  // ---- backward layer 1: dEdD[d] = sum_j da1[j] * W1[d][j] ----
  float dE[kND];
  #pragma unroll
  for (int d = 0; d < kND; ++d) dE[d] = 0.f;
  #pragma unroll
  for (int j = 0; j < kH; j += 4) {
    const float g0 = da1[j+0], g1 = da1[j+1], g2 = da1[j+2], g3 = da1[j+3];
    #pragma unroll
    for (int d = 0; d < kND; ++d) {
      const float* w = &sW1[d * kH + j];   // 4 contiguous floats
      dE[d] += g0 * w[0] + g1 * w[1] + g2 * w[2] + g3 * w[3];
    }
  }
  #pragma unroll
  for (int d = 0; d < kND; ++d) dEdD[(size_t)atom * kNDP + d] = dE[d];
}

// 128 rows per block. xd rows staged through LDS with coalesced float4 loads
// (fixes stride-220B per-lane global reads: xd is fetched exactly once from
// HBM in contiguous wave segments). Per-thread LDS row reads are stride-55
// (odd) -> 2-way bank aliasing, free on CDNA4.
constexpr int kFB = 128;                 // rows per forces block
__global__ __launch_bounds__(kFB)
void forces_kernel(const float* __restrict__ xd,
                   const int* __restrict__ xd_indx,
                   const int* __restrict__ unique_j,
                   const float* __restrict__ dEdD,
                   float* __restrict__ out_forces) {  // [3*kNAtoms], pre-zeroed
  __shared__ float sxd[kFB * kND];       // 27.5 KiB
  const int t = threadIdx.x;
  const int base = blockIdx.x * kFB;
  const int n = min(kFB, kNRows - base); // tail block: 3e6 % 128 = 64 rows

  // ---- coalesced float4 staging of n rows (n*55 floats; divisible by 4
  // for n=128 (7040) and n=64 (3520); generic remainder loop kept anyway) ----
  {
    const int nfl = n * kND;
    const int nf4 = nfl >> 2;
    const float4* __restrict__ src4 =
        reinterpret_cast<const float4*>(xd + (size_t)base * kND);  // 16B-aligned: base*220B, base mult of 4... base*55*4B = base*220B; base=128b -> 28160B*b, aligned
    float4* __restrict__ dst4 = reinterpret_cast<float4*>(sxd);
    for (int i = t; i < nf4; i += kFB) dst4[i] = src4[i];
    for (int i = (nf4 << 2) + t; i < nfl; i += kFB)
      sxd[i] = xd[(size_t)base * kND + i];
  }
  __syncthreads();

  if (t >= n) return;
  const int r   = base + t;
  const int ai  = xd_indx[3 * r + 0];
  const int dim = xd_indx[3 * r + 2];
  const int j   = unique_j[r];

  const float* __restrict__ xr = &sxd[t * kND];
  const float* __restrict__ gr = dEdD + (size_t)ai * kNDP;     // 16B-aligned
  const float4* __restrict__ g4 = reinterpret_cast<const float4*>(gr);

  float s = 0.f;
  #pragma unroll
  for (int q = 0; q < 13; ++q) {
    const float4 g = g4[q];
    s += xr[4*q+0] * g.x + xr[4*q+1] * g.y + xr[4*q+2] * g.z + xr[4*q+3] * g.w;
  }
  s += xr[52] * gr[52] + xr[53] * gr[53] + xr[54] * gr[54];

  atomicAdd(&out_forces[3 * j + dim], s);
}

extern "C" void kernel_launch(void* const* d_in, const int* in_sizes, int n_in,
                              void* d_out, int out_size, void* d_ws, size_t ws_size,
                              hipStream_t stream) {
  const float* x        = (const float*)d_in[0];
  const float* xd       = (const float*)d_in[1];
  const int*   indices  = (const int*)d_in[2];
  // d_in[3] = atoms_per_structure (unused: indices already give the segments)
  // d_in[4] = types (unused for multi_element_option == 1)
  const int*   xd_indx  = (const int*)d_in[5];
  const int*   unique_j = (const int*)d_in[6];
  const float* W1 = (const float*)d_in[7];
  const float* b1 = (const float*)d_in[8];
  const float* W2 = (const float*)d_in[9];
  const float* b2 = (const float*)d_in[10];
  const float* W3 = (const float*)d_in[11];
  const float* b3 = (const float*)d_in[12];

  float* out  = (float*)d_out;     // [0,500) energy, [500,150500) forces
  float* dEdD = (float*)d_ws;      // kNAtoms * kNDP floats = 11.2 MB

  zero_out_kernel<<<(kOutN + 255) / 256, 256, 0, stream>>>(out, kOutN);
  mlp_kernel<<<(kNAtoms + 127) / 128, 128, 0, stream>>>(
      x, indices, W1, b1, W2, b2, W3, b3, out, dEdD);
  forces_kernel<<<(kNRows + kFB - 1) / kFB, kFB, 0, stream>>>(
      xd, xd_indx, unique_j, dEdD, out + kNConf);
}

// Round 4
// 1144.858 us; speedup vs baseline: 1.0246x; 1.0246x over previous
//
#include <hip/hip_runtime.h>

typedef float f4v __attribute__((ext_vector_type(4)));

constexpr int kNAtoms = 50000;
constexpr int kNConf  = 500;
constexpr int kNRows  = 3000000;   // 3 * NPAIRS
constexpr int kND     = 55;
constexpr int kNDP    = 56;        // padded row stride for dEdD (224 B, 16B-aligned)
constexpr int kOutN   = kNConf + 3 * kNAtoms;  // 150500

__global__ void zero_out_kernel(float* __restrict__ out, int n) {
  int i = blockIdx.x * blockDim.x + threadIdx.x;
  if (i < n) out[i] = 0.0f;
}

// GEMM-tiled fused MLP fwd+bwd. Block = 64 atoms, 256 threads.
// Thread (ta = t>>4, tb = t&15) owns a 4x4 tile: atoms ta*4..+3, cols tb*4..+3.
// Activation tiles use row stride 68: av b128 reads are 4 addrs/wave, rows 4
// apart -> bank offset (4*68)%32 = 16 -> two 2-way groups = free. Weight tiles
// stride 64: row is wave-uniform per sub-read, 16 b128 slots span banks 2-way.
// All inner loops are d-quads: 8x ds_read_b128 per 64 FMA -> VALU-bound.
constexpr int kTS = 68;   // activation tile row stride (floats)
__global__ __launch_bounds__(256)
void mlp_kernel(const float* __restrict__ x,
                const int* __restrict__ indices,
                const float* __restrict__ W1, const float* __restrict__ b1,
                const float* __restrict__ W2, const float* __restrict__ b2,
                const float* __restrict__ W3, const float* __restrict__ b3,
                float* __restrict__ out_energy,   // [kNConf], pre-zeroed
                float* __restrict__ dEdD) {       // [kNAtoms * kNDP]
  __shared__ float sX[64 * kTS];     // x tile; later da1 tile
  __shared__ float sH1[64 * kTS];    // h1 tile (kept for backward)
  __shared__ float sDa2[64 * kTS];   // da2 tile
  __shared__ float sW1v[56 * 64];    // W1[d][k], row 55 = 0
  __shared__ float sW1T[64 * 64];    // W1T[j][d], cols 55..63 = 0
  __shared__ float sW2v[64 * 64];    // W2[j][k]
  __shared__ float sW2T[64 * 64];    // W2T[k][j]
  __shared__ float sW3v[64], sb1v[64], sb2v[64];

  const int t  = threadIdx.x;
  const int tb = t & 15;
  const int ta = t >> 4;
  const int a0 = blockIdx.x * 64;

  for (int i = t; i < 56 * 64; i += 256) sW1v[i] = (i < 55 * 64) ? W1[i] : 0.0f;
  for (int i = t; i < 64 * 64; i += 256) {
    int j = i >> 6, d = i & 63;
    sW1T[i] = (d < 55) ? W1[d * 64 + j] : 0.0f;   // L2-hot tiny reads
  }
  for (int i = t; i < 64 * 64; i += 256) sW2v[i] = W2[i];
  for (int i = t; i < 64 * 64; i += 256) {
    int k = i >> 6, j = i & 63;
    sW2T[i] = W2[j * 64 + k];
  }
  if (t < 64) { sW3v[t] = W3[t]; sb1v[t] = b1[t]; sb2v[t] = b2[t]; }
  // x tile: row r (atom a0+r), col c -> sX[r*kTS + c]; col 55 zeroed (pad quad)
  for (int i = t; i < 64 * 55; i += 256) {
    int r = i / 55, c = i % 55;
    int atom = a0 + r;
    sX[r * kTS + c] = (atom < kNAtoms) ? x[(size_t)atom * kND + c] : 0.0f;
  }
  if (t < 64) sX[t * kTS + 55] = 0.0f;
  const float b3v = b3[0];
  __syncthreads();

  // ---- GEMM1: h1 = tanh(x @ W1 + b1), K = 56 (last d-col is zero pad) ----
  float acc[4][4];
  #pragma unroll
  for (int i = 0; i < 4; ++i)
    #pragma unroll
    for (int q = 0; q < 4; ++q) acc[i][q] = sb1v[tb * 4 + q];
  #pragma unroll 2
  for (int dq = 0; dq < 14; ++dq) {
    const int d0 = dq * 4;
    const f4v bv0 = *(const f4v*)&sW1v[(d0 + 0) * 64 + tb * 4];
    const f4v bv1 = *(const f4v*)&sW1v[(d0 + 1) * 64 + tb * 4];
    const f4v bv2 = *(const f4v*)&sW1v[(d0 + 2) * 64 + tb * 4];
    const f4v bv3 = *(const f4v*)&sW1v[(d0 + 3) * 64 + tb * 4];
    #pragma unroll
    for (int i = 0; i < 4; ++i) {
      const f4v av = *(const f4v*)&sX[(ta * 4 + i) * kTS + d0];
      #pragma unroll
      for (int q = 0; q < 4; ++q)
        acc[i][q] += av[0] * bv0[q] + av[1] * bv1[q]
                   + av[2] * bv2[q] + av[3] * bv3[q];
    }
  }
  #pragma unroll
  for (int i = 0; i < 4; ++i) {
    f4v hv;
    #pragma unroll
    for (int q = 0; q < 4; ++q) hv[q] = tanhf(acc[i][q]);
    *(f4v*)&sH1[(ta * 4 + i) * kTS + tb * 4] = hv;
  }
  __syncthreads();

  // ---- GEMM2: h2 = tanh(h1 @ W2 + b2); E partial; da2 = W3*(1-h2^2) ----
  #pragma unroll
  for (int i = 0; i < 4; ++i)
    #pragma unroll
    for (int q = 0; q < 4; ++q) acc[i][q] = sb2v[tb * 4 + q];
  #pragma unroll 2
  for (int jq = 0; jq < 16; ++jq) {
    const int j0 = jq * 4;
    const f4v bv0 = *(const f4v*)&sW2v[(j0 + 0) * 64 + tb * 4];
    const f4v bv1 = *(const f4v*)&sW2v[(j0 + 1) * 64 + tb * 4];
    const f4v bv2 = *(const f4v*)&sW2v[(j0 + 2) * 64 + tb * 4];
    const f4v bv3 = *(const f4v*)&sW2v[(j0 + 3) * 64 + tb * 4];
    #pragma unroll
    for (int i = 0; i < 4; ++i) {
      const f4v av = *(const f4v*)&sH1[(ta * 4 + i) * kTS + j0];
      #pragma unroll
      for (int q = 0; q < 4; ++q)
        acc[i][q] += av[0] * bv0[q] + av[1] * bv1[q]
                   + av[2] * bv2[q] + av[3] * bv3[q];
    }
  }
  float epart[4];
  {
    const f4v w3 = *(const f4v*)&sW3v[tb * 4];
    #pragma unroll
    for (int i = 0; i < 4; ++i) {
      f4v dv; float e = 0.0f;
      #pragma unroll
      for (int q = 0; q < 4; ++q) {
        const float h2 = tanhf(acc[i][q]);
        e += h2 * w3[q];
        dv[q] = w3[q] * (1.0f - h2 * h2);
      }
      epart[i] = e;
      *(f4v*)&sDa2[(ta * 4 + i) * kTS + tb * 4] = dv;
    }
  }
  // reduce energy partials across the 16 tb-lanes (contiguous in the wave)
  #pragma unroll
  for (int off = 8; off >= 1; off >>= 1)
    #pragma unroll
    for (int i = 0; i < 4; ++i) epart[i] += __shfl_xor(epart[i], off, 16);
  if (tb == 0) {
    #pragma unroll
    for (int i = 0; i < 4; ++i) {
      const int atom = a0 + ta * 4 + i;
      if (atom < kNAtoms)
        atomicAdd(&out_energy[indices[atom]], epart[i] + b3v);
    }
  }
  __syncthreads();

  // ---- backward2: da1 = (1 - h1^2) * (da2 @ W2T), written into sX ----
  #pragma unroll
  for (int i = 0; i < 4; ++i)
    #pragma unroll
    for (int q = 0; q < 4; ++q) acc[i][q] = 0.0f;
  #pragma unroll 2
  for (int kq = 0; kq < 16; ++kq) {
    const int k0 = kq * 4;
    const f4v bv0 = *(const f4v*)&sW2T[(k0 + 0) * 64 + tb * 4];
    const f4v bv1 = *(const f4v*)&sW2T[(k0 + 1) * 64 + tb * 4];
    const f4v bv2 = *(const f4v*)&sW2T[(k0 + 2) * 64 + tb * 4];
    const f4v bv3 = *(const f4v*)&sW2T[(k0 + 3) * 64 + tb * 4];
    #pragma unroll
    for (int i = 0; i < 4; ++i) {
      const f4v av = *(const f4v*)&sDa2[(ta * 4 + i) * kTS + k0];
      #pragma unroll
      for (int q = 0; q < 4; ++q)
        acc[i][q] += av[0] * bv0[q] + av[1] * bv1[q]
                   + av[2] * bv2[q] + av[3] * bv3[q];
    }
  }
  #pragma unroll
  for (int i = 0; i < 4; ++i) {
    const f4v hv = *(const f4v*)&sH1[(ta * 4 + i) * kTS + tb * 4];
    f4v dv;
    #pragma unroll
    for (int q = 0; q < 4; ++q) dv[q] = acc[i][q] * (1.0f - hv[q] * hv[q]);
    *(f4v*)&sX[(ta * 4 + i) * kTS + tb * 4] = dv;   // sX now holds da1
  }
  __syncthreads();

  // ---- backward1: dEdD = da1 @ W1T (cols 55..63 of W1T are 0) ----
  #pragma unroll
  for (int i = 0; i < 4; ++i)
    #pragma unroll
    for (int q = 0; q < 4; ++q) acc[i][q] = 0.0f;
  #pragma unroll 2
  for (int jq = 0; jq < 16; ++jq) {
    const int j0 = jq * 4;
    const f4v bv0 = *(const f4v*)&sW1T[(j0 + 0) * 64 + tb * 4];
    const f4v bv1 = *(const f4v*)&sW1T[(j0 + 1) * 64 + tb * 4];
    const f4v bv2 = *(const f4v*)&sW1T[(j0 + 2) * 64 + tb * 4];
    const f4v bv3 = *(const f4v*)&sW1T[(j0 + 3) * 64 + tb * 4];
    #pragma unroll
    for (int i = 0; i < 4; ++i) {
      const f4v av = *(const f4v*)&sX[(ta * 4 + i) * kTS + j0];
      #pragma unroll
      for (int q = 0; q < 4; ++q)
        acc[i][q] += av[0] * bv0[q] + av[1] * bv1[q]
                   + av[2] * bv2[q] + av[3] * bv3[q];
    }
  }
  if (tb < 14) {   // cols tb*4..+3 < 56 (col 55 = pad, value 0, never consumed)
    #pragma unroll
    for (int i = 0; i < 4; ++i) {
      const int atom = a0 + ta * 4 + i;
      if (atom < kNAtoms) {
        f4v ov; ov[0]=acc[i][0]; ov[1]=acc[i][1]; ov[2]=acc[i][2]; ov[3]=acc[i][3];
        *(f4v*)&dEdD[(size_t)atom * kNDP + tb * 4] = ov;
      }
    }
  }
}

// 128 rows/block. dEdD rows gathered into registers BEFORE the LDS staging of
// xd (gather latency hides under the staging stream). xd / index streams use
// non-temporal loads so they don't evict the 11 MB dEdD table from L2/L3.
constexpr int kFB = 128;
__global__ __launch_bounds__(kFB)
void forces_kernel(const float* __restrict__ xd,
                   const int* __restrict__ xd_indx,
                   const int* __restrict__ unique_j,
                   const float* __restrict__ dEdD,
                   float* __restrict__ out_forces) {  // [3*kNAtoms], pre-zeroed
  __shared__ float sxd[kFB * kND];       // 27.5 KiB
  const int t = threadIdx.x;
  const int base = blockIdx.x * kFB;
  const int n = min(kFB, kNRows - base);

  // ---- early: load indices and issue the 14-quad dEdD gather ----
  int ai = 0, dim = 0, j = 0;
  f4v g[14];
  if (t < n) {
    const int r = base + t;
    ai  = __builtin_nontemporal_load(&xd_indx[3 * r + 0]);
    dim = __builtin_nontemporal_load(&xd_indx[3 * r + 2]);
    j   = __builtin_nontemporal_load(&unique_j[r]);
    const f4v* __restrict__ g4 =
        reinterpret_cast<const f4v*>(dEdD + (size_t)ai * kNDP);
    #pragma unroll
    for (int q = 0; q < 14; ++q) g[q] = g4[q];   // cached loads (L2/L3-resident)
  }

  // ---- coalesced non-temporal staging of xd rows into LDS ----
  {
    const int nfl = n * kND;
    const int nf4 = nfl >> 2;     // exact for n=128 and the n=64 tail
    const f4v* __restrict__ src4 =
        reinterpret_cast<const f4v*>(xd + (size_t)base * kND);
    f4v* __restrict__ dst4 = reinterpret_cast<f4v*>(sxd);
    for (int i = t; i < nf4; i += kFB)
      dst4[i] = __builtin_nontemporal_load(&src4[i]);
    for (int i = (nf4 << 2) + t; i < nfl; i += kFB)
      sxd[i] = __builtin_nontemporal_load(&xd[(size_t)base * kND + i]);
  }
  __syncthreads();

  if (t >= n) return;
  const float* __restrict__ xr = &sxd[t * kND];   // stride 55: 2-way banks, free

  float s = 0.0f;
  #pragma unroll
  for (int q = 0; q < 13; ++q) {
    s += xr[4*q+0] * g[q][0] + xr[4*q+1] * g[q][1]
       + xr[4*q+2] * g[q][2] + xr[4*q+3] * g[q][3];
  }
  s += xr[52] * g[13][0] + xr[53] * g[13][1] + xr[54] * g[13][2];

  atomicAdd(&out_forces[3 * j + dim], s);
}

extern "C" void kernel_launch(void* const* d_in, const int* in_sizes, int n_in,
                              void* d_out, int out_size, void* d_ws, size_t ws_size,
                              hipStream_t stream) {
  const float* x        = (const float*)d_in[0];
  const float* xd       = (const float*)d_in[1];
  const int*   indices  = (const int*)d_in[2];
  // d_in[3] = atoms_per_structure (unused), d_in[4] = types (unused)
  const int*   xd_indx  = (const int*)d_in[5];
  const int*   unique_j = (const int*)d_in[6];
  const float* W1 = (const float*)d_in[7];
  const float* b1 = (const float*)d_in[8];
  const float* W2 = (const float*)d_in[9];
  const float* b2 = (const float*)d_in[10];
  const float* W3 = (const float*)d_in[11];
  const float* b3 = (const float*)d_in[12];

  float* out  = (float*)d_out;     // [0,500) energy, [500,150500) forces
  float* dEdD = (float*)d_ws;      // kNAtoms * kNDP floats = 11.2 MB

  zero_out_kernel<<<(kOutN + 255) / 256, 256, 0, stream>>>(out, kOutN);
  mlp_kernel<<<(kNAtoms + 63) / 64, 256, 0, stream>>>(
      x, indices, W1, b1, W2, b2, W3, b3, out, dEdD);
  forces_kernel<<<(kNRows + kFB - 1) / kFB, kFB, 0, stream>>>(
      xd, xd_indx, unique_j, dEdD, out + kNConf);
}